// Round 17
// baseline (146.855 us; speedup 1.0000x reference)
//
#include <hip/hip_runtime.h>
#include <hip/hip_bf16.h>

// AttnPredictor round 17: kA = r16 verbatim (MFMA M-range). kB widened:
// 32 b per block, 512 threads, grid 512 (2 blocks/CU, same 16 waves/CU) —
// halves the per-b M[h] L2 re-read and doubles MFMA per staged load.
//  kA (512 blocks):
//   [0,64)    P1: w = softmax_d(z*(a@Wqk + bqk)/sqrt192), attn_weights
//   [64,224)  U[h,d,k] = Wfv[d,:]·W1[h,0:128,k] ; dt==4: c0'
//   [224,480) M_T (MFMA, 8 blocks/h); c1 = b2@W1o + b1o (kt==0)
//   [480,512) W1g'[h][20][256] (rows 18,19 zero)
//  kB (512 blocks, XCD-swizzled h, 32 b per block):
//   g(regs, rank-18) -> P (bf16 LDS) -> effect = relu(P@M+c1)·W2o+b2o (MFMA)

typedef __attribute__((ext_vector_type(8))) short bf16x8;
typedef __attribute__((ext_vector_type(4))) short bf16x4;
typedef __attribute__((ext_vector_type(4))) float f32x4;

__device__ __forceinline__ short f2bf(float x) {
  unsigned u = __float_as_uint(x);
  u += 0x7fffu + ((u >> 16) & 1u);          // round-to-nearest-even
  return (short)(u >> 16);
}
__device__ __forceinline__ float bf2f(unsigned short u) {
  return __uint_as_float((unsigned)u << 16);
}

__global__ __launch_bounds__(256) void kA_prep(
    const float* __restrict__ feat, const float* __restrict__ act,
    const float* __restrict__ Wq, const float* __restrict__ bq,
    const float* __restrict__ Wk,
    const float* __restrict__ Wav, const float* __restrict__ bav,
    const float* __restrict__ Wfv, const float* __restrict__ bfv,
    const float* __restrict__ W1, const float* __restrict__ b1,
    const float* __restrict__ W2, const float* __restrict__ b2,
    const float* __restrict__ W1o, const float* __restrict__ b1o,
    float* __restrict__ ws_w, float* __restrict__ ws_U,
    float* __restrict__ ws_c0, unsigned short* __restrict__ ws_Mbf,
    float* __restrict__ ws_c1, float* __restrict__ ws_W1g,
    float* __restrict__ out_aw) {
  __shared__ __align__(16) char smem[33792];  // aliased per range
  float* sh = (float*)smem;
  const int bx = blockIdx.x;
  const int t = threadIdx.x;

  if (bx < 64) {
    // ---------------- P1: softmax weights + attn_weights (8 b per block)
    const int b0 = bx * 8;
    float* sWk = sh;                        // [192 c][32 d] transposed
    float* sA  = sh + 6144;                 // act [8][18]
    float* sQk = sh + 6320;                 // [19 j][32 d] (row 18 = bq row)
    float* sW  = sh + 6944;                 // [8][32]
#pragma unroll
    for (int i = 0; i < 24; ++i) {
      const int idx = i * 256 + t;          // idx = d*192 + c
      sWk[(idx % 192) * 32 + (idx / 192)] = Wk[idx];
    }
    if (t < 144) sA[t] = act[b0 * 18 + t];
    __syncthreads();
    for (int o = t; o < 608; o += 256) {    // Wqk[j][d]; j==18 -> bqk
      const int j = o >> 5, d = o & 31;
      const float* arow = (j < 18) ? (Wq + j * 192) : bq;
      float acc = 0.f;
      for (int c = 0; c < 192; ++c) acc += arow[c] * sWk[c * 32 + d];
      sQk[o] = acc;
    }
    __syncthreads();
    {
      const int bi = t >> 5, d = t & 31;
      float dot = sQk[18 * 32 + d];
#pragma unroll
      for (int j = 0; j < 18; ++j) dot += sA[bi * 18 + j] * sQk[j * 32 + d];
      const float z = feat[b0 * 32 + t];
      float sc = z * dot * 0.07216878364870322f;   // 1/sqrt(192)
      float mx = sc;
#pragma unroll
      for (int off = 16; off >= 1; off >>= 1) mx = fmaxf(mx, __shfl_xor(mx, off, 64));
      const float e = __expf(sc - mx);
      float s = e;
#pragma unroll
      for (int off = 16; off >= 1; off >>= 1) s += __shfl_xor(s, off, 64);
      const float w = e / s;
      ws_w[b0 * 32 + t] = w;
      sW[t] = w;
    }
    __syncthreads();
#pragma unroll
    for (int i = 0; i < 32; ++i)
      out_aw[b0 * 1024 + i * 256 + t] = sW[(i >> 2) * 32 + (t & 31)];

  } else if (bx < 224) {
    // ---------------- U range: 5 blocks per h (dt<4: 8 d's; dt==4: c0')
    const int r = bx - 64;
    const int h = r / 5, dt = r % 5;
    float* sF = sh;                         // [8][128] Wfv tile (or bfv)
    if (dt < 4) {
#pragma unroll
      for (int i = 0; i < 4; ++i) sF[i * 256 + t] = Wfv[dt * 1024 + i * 256 + t];
    } else {
      if (t < 128) sF[t] = bfv[t];
    }
    __syncthreads();
    if (dt < 4) {
      float acc[8];
#pragma unroll
      for (int dd = 0; dd < 8; ++dd) acc[dd] = 0.f;
#pragma unroll 4
      for (int fc = 0; fc < 32; ++fc) {
        float w1v[4];
#pragma unroll
        for (int u = 0; u < 4; ++u) w1v[u] = W1[(h * 192 + fc * 4 + u) * 256 + t];
#pragma unroll
        for (int dd = 0; dd < 8; ++dd) {
          float4 f4 = *(const float4*)(sF + dd * 128 + fc * 4);
          acc[dd] += f4.x * w1v[0] + f4.y * w1v[1] + f4.z * w1v[2] + f4.w * w1v[3];
        }
      }
#pragma unroll
      for (int dd = 0; dd < 8; ++dd)
        ws_U[(h * 32 + dt * 8 + dd) * 256 + t] = acc[dd];
    } else {
      float acc = b1[h * 256 + t];
      for (int fc = 0; fc < 32; ++fc) {
        float w1v[4];
#pragma unroll
        for (int u = 0; u < 4; ++u) w1v[u] = W1[(h * 192 + fc * 4 + u) * 256 + t];
        float4 f4 = *(const float4*)(sF + fc * 4);
        acc += f4.x * w1v[0] + f4.y * w1v[1] + f4.z * w1v[2] + f4.w * w1v[3];
      }
      // fold bav·W1[h,128:192,k] into c0 (bav[u] uniform -> s_load)
      for (int u = 0; u < 64; ++u)
        acc += bav[u] * W1[(h * 192 + 128 + u) * 256 + t];
      ws_c0[h * 256 + t] = acc;
    }

  } else if (bx < 480) {
    // ---------------- M range (MFMA): 8 blocks/h, 32 k1-rows each.
    const int r = bx - 224;
    const int h = r >> 3, kt = r & 7;
    short* sW2 = (short*)smem;              // [32][206] bf16 A-tile
    short* sB  = (short*)(smem + 13184);    // [256][38] bf16 B-chunk

    for (int i = t; i < 6144; i += 256) {
      const int row = i / 192, col = i - row * 192;
      sW2[row * 206 + col] = f2bf(W2[h * 49152 + (kt * 32 + row) * 192 + col]);
    }
    const int wv = t >> 6, lane = t & 63;
    const int quad = lane >> 4, l15 = lane & 15;

    f32x4 acc[2][4];
    const f32x4 zero = {0.f, 0.f, 0.f, 0.f};
#pragma unroll
    for (int mt = 0; mt < 2; ++mt)
#pragma unroll
      for (int nt = 0; nt < 4; ++nt) acc[mt][nt] = zero;
    float c1acc = 0.f;

    for (int kk = 0; kk < 6; ++kk) {
      __syncthreads();
#pragma unroll
      for (int vp = 0; vp < 32; vp += 2) {
        const float f0 = W1o[h * 49152 + (kk * 32 + vp) * 256 + t];
        const float f1 = W1o[h * 49152 + (kk * 32 + vp + 1) * 256 + t];
        const unsigned pack =
            ((unsigned)(unsigned short)f2bf(f1) << 16) | (unsigned short)f2bf(f0);
        *(unsigned*)(sB + t * 38 + vp) = pack;
      }
      __syncthreads();
      if (kt == 0) {
#pragma unroll
        for (int vp = 0; vp < 32; ++vp)
          c1acc += b2[h * 192 + kk * 32 + vp] * bf2f((unsigned short)sB[t * 38 + vp]);
      }
      bf16x8 a0[2];
#pragma unroll
      for (int mt = 0; mt < 2; ++mt)
        a0[mt] = *(const bf16x8*)(sW2 + (mt * 16 + l15) * 206 + kk * 32 + quad * 8);
#pragma unroll
      for (int nt = 0; nt < 4; ++nt) {
        bf16x8 b0 = *(const bf16x8*)(sB + (wv * 64 + nt * 16 + l15) * 38 + quad * 8);
#pragma unroll
        for (int mt = 0; mt < 2; ++mt)
          acc[mt][nt] = __builtin_amdgcn_mfma_f32_16x16x32_bf16(a0[mt], b0, acc[mt][nt], 0, 0, 0);
      }
    }
#pragma unroll
    for (int mt = 0; mt < 2; ++mt) {
#pragma unroll
      for (int nt = 0; nt < 4; ++nt) {
        const int col = wv * 64 + nt * 16 + l15;
        const unsigned p0 = ((unsigned)(unsigned short)f2bf(acc[mt][nt][1]) << 16) |
                            (unsigned short)f2bf(acc[mt][nt][0]);
        const unsigned p1 = ((unsigned)(unsigned short)f2bf(acc[mt][nt][3]) << 16) |
                            (unsigned short)f2bf(acc[mt][nt][2]);
        unsigned* dst = (unsigned*)(ws_Mbf + (size_t)(h * 256 + col) * 256 +
                                    kt * 32 + mt * 16 + quad * 4);
        dst[0] = p0; dst[1] = p1;
      }
    }
    if (kt == 0) ws_c1[h * 256 + t] = c1acc + b1o[h * 256 + t];

  } else {
    // ---------------- W1g' range: 1 block per h.
    const int h = bx - 480;
    float accj[18];
#pragma unroll
    for (int j = 0; j < 18; ++j) accj[j] = 0.f;
#pragma unroll 4
    for (int u = 0; u < 64; ++u) {
      const float w1v = W1[(h * 192 + 128 + u) * 256 + t];
#pragma unroll
      for (int j = 0; j < 18; ++j)
        accj[j] += Wav[j * 64 + u] * w1v;
    }
#pragma unroll
    for (int j = 0; j < 18; ++j)
      ws_W1g[(h * 20 + j) * 256 + t] = accj[j];
    ws_W1g[(h * 20 + 18) * 256 + t] = 0.f;
    ws_W1g[(h * 20 + 19) * 256 + t] = 0.f;
  }
}

// ---------------------------------------------------------------- kB: 32 b / 512 thr; G(regs)+P -> MFMA -> effect
__global__ __launch_bounds__(512) void kB_main(
    const float* __restrict__ feat, const float* __restrict__ act,
    const float* __restrict__ ws_w, const float* __restrict__ ws_U,
    const float* __restrict__ ws_W1g, const float* __restrict__ ws_c0,
    const unsigned short* __restrict__ ws_Mbf, const float* __restrict__ ws_c1,
    const float* __restrict__ W2o, const float* __restrict__ b2o,
    float* __restrict__ out_eff) {
  const int bx = blockIdx.x;
  const int h = (bx & 7) * 4 + ((bx >> 3) & 3);   // XCD swizzle (bijective in bx&31)
  const int bt = bx >> 5;                   // 32 b per block, bt in [0,16)
  const int b0 = bt * 32;
  const int t = threadIdx.x;

  __shared__ __align__(16) char smem[28672];
  short* sP   = (short*)smem;               // [32][264] bf16 : 16896 B
  float* sA   = (float*)(smem + 16896);     // [32][20] act, cols 18-19 zero
  float* sZ   = (float*)(smem + 19456);     // [32][32]
  float* sWw  = (float*)(smem + 23552);     // [32][32]
  float* sRed = (float*)(smem + 27648);     // [32][8]

  // ---- stage act (zero-padded), z, w into LDS
  {
#pragma unroll
    for (int i = 0; i < 2; ++i) {
      sZ[i * 512 + t]  = feat[b0 * 32 + i * 512 + t];
      sWw[i * 512 + t] = ws_w[b0 * 32 + i * 512 + t];
    }
    for (int i = t; i < 640; i += 512) {
      const int row = i / 20, col = i - row * 20;
      sA[i] = (col < 18) ? act[(b0 + row) * 18 + col] : 0.f;
    }
  }
  __syncthreads();

  // ---- fused G(registers, rank-18) + P: thread (bq = t>>6 -> rows bq*4..+3
  //      of 32; kg = t&63 -> cols kg*4..+3)
  {
    const int bq = t >> 6, kg = t & 63;
    float g[4][4];

    // G: g[r][c] = c0'[c] + sum_{j<20} a[row][j]*W1g'[h][j][col]
    {
      float4 c04 = *(const float4*)(ws_c0 + h * 256 + kg * 4);
#pragma unroll
      for (int r = 0; r < 4; ++r) {
        g[r][0] = c04.x; g[r][1] = c04.y; g[r][2] = c04.z; g[r][3] = c04.w;
      }
      const float* Wgp = ws_W1g + (h * 20) * 256 + kg * 4;
#pragma unroll
      for (int jc = 0; jc < 5; ++jc) {
        float w1q[4][4];
#pragma unroll
        for (int u = 0; u < 4; ++u) {
          float4 w4 = *(const float4*)(Wgp + (jc * 4 + u) * 256);
          w1q[u][0] = w4.x; w1q[u][1] = w4.y; w1q[u][2] = w4.z; w1q[u][3] = w4.w;
        }
        float a4[4][4];
#pragma unroll
        for (int r = 0; r < 4; ++r) {
          float4 av = *(const float4*)(sA + (bq * 4 + r) * 20 + jc * 4);
          a4[r][0] = av.x; a4[r][1] = av.y; a4[r][2] = av.z; a4[r][3] = av.w;
        }
#pragma unroll
        for (int u = 0; u < 4; ++u)
#pragma unroll
          for (int r = 0; r < 4; ++r)
#pragma unroll
            for (int c = 0; c < 4; ++c)
              g[r][c] += a4[r][u] * w1q[u][c];
      }
    }

    // P: acc[r][c] = sum_d w_d*relu(z_d*U[d][col] + g[r][c])
    float acc[4][4];
#pragma unroll
    for (int r = 0; r < 4; ++r) {
      acc[r][0] = 0.f; acc[r][1] = 0.f; acc[r][2] = 0.f; acc[r][3] = 0.f;
    }
    const float* Up = ws_U + h * 8192 + kg * 4;
#pragma unroll
    for (int dc = 0; dc < 8; ++dc) {
      float uc[4][4];
#pragma unroll
      for (int dd = 0; dd < 4; ++dd) {
        float4 u4 = *(const float4*)(Up + (dc * 4 + dd) * 256);
        uc[dd][0] = u4.x; uc[dd][1] = u4.y; uc[dd][2] = u4.z; uc[dd][3] = u4.w;
      }
      float zr[4][4], wr[4][4];
#pragma unroll
      for (int r = 0; r < 4; ++r) {
        float4 z4 = *(const float4*)(sZ + (bq * 4 + r) * 32 + dc * 4);
        float4 w4 = *(const float4*)(sWw + (bq * 4 + r) * 32 + dc * 4);
        zr[r][0] = z4.x; zr[r][1] = z4.y; zr[r][2] = z4.z; zr[r][3] = z4.w;
        wr[r][0] = w4.x; wr[r][1] = w4.y; wr[r][2] = w4.z; wr[r][3] = w4.w;
      }
#pragma unroll
      for (int dd = 0; dd < 4; ++dd) {
#pragma unroll
        for (int r = 0; r < 4; ++r) {
#pragma unroll
          for (int c = 0; c < 4; ++c)
            acc[r][c] += wr[r][dd] * fmaxf(zr[r][dd] * uc[dd][c] + g[r][c], 0.f);
        }
      }
    }
#pragma unroll
    for (int r = 0; r < 4; ++r) {
      bf16x4 p;
#pragma unroll
      for (int c = 0; c < 4; ++c) p[c] = f2bf(acc[r][c]);
      *(bf16x4*)(sP + (bq * 4 + r) * 264 + kg * 4) = p;
    }
  }
  __syncthreads();

  // ---- MFMA: wave wv owns k2 [wv*32, wv*32+32); rows 0..31 (2 mt tiles)
  {
    const int wv = t >> 6;
    const int lane = t & 63;
    const int quad = lane >> 4, l15 = lane & 15;

    f32x4 acc[2][2];
    const f32x4 zero = {0.f, 0.f, 0.f, 0.f};
#pragma unroll
    for (int mt = 0; mt < 2; ++mt)
#pragma unroll
      for (int nt = 0; nt < 2; ++nt) acc[mt][nt] = zero;

    float c1r[2], w2r[2];
#pragma unroll
    for (int nt = 0; nt < 2; ++nt) {
      const int col = wv * 32 + nt * 16 + l15;
      c1r[nt] = ws_c1[h * 256 + col];
      w2r[nt] = W2o[h * 256 + col];
    }
    const unsigned short* Mp = ws_Mbf + (size_t)(h * 256 + wv * 32) * 256;

#pragma unroll
    for (int kc = 0; kc < 8; ++kc) {
      bf16x8 a0[2];
#pragma unroll
      for (int mt = 0; mt < 2; ++mt)
        a0[mt] = *(const bf16x8*)(sP + (mt * 16 + l15) * 264 + kc * 32 + quad * 8);
      bf16x8 bfr[2];
#pragma unroll
      for (int nt = 0; nt < 2; ++nt)
        bfr[nt] = *(const bf16x8*)(Mp + (nt * 16 + l15) * 256 + kc * 32 + quad * 8);
#pragma unroll
      for (int nt = 0; nt < 2; ++nt)
#pragma unroll
        for (int mt = 0; mt < 2; ++mt)
          acc[mt][nt] = __builtin_amdgcn_mfma_f32_16x16x32_bf16(a0[mt], bfr[nt], acc[mt][nt], 0, 0, 0);
    }
#pragma unroll
    for (int mt = 0; mt < 2; ++mt) {
#pragma unroll
      for (int r = 0; r < 4; ++r) {
        float s = fmaxf(acc[mt][0][r] + c1r[0], 0.f) * w2r[0]
                + fmaxf(acc[mt][1][r] + c1r[1], 0.f) * w2r[1];
        s += __shfl_xor(s, 1, 64);
        s += __shfl_xor(s, 2, 64);
        s += __shfl_xor(s, 4, 64);
        s += __shfl_xor(s, 8, 64);
        if (l15 == 0) sRed[(mt * 16 + quad * 4 + r) * 8 + wv] = s;
      }
    }
  }
  __syncthreads();
  if (t < 32) {
    float v = b2o[h];
#pragma unroll
    for (int wv = 0; wv < 8; ++wv) v += sRed[t * 8 + wv];
    out_eff[(b0 + t) * 32 + h] = v;
  }
}

// ----------------------------------------------------------------
extern "C" void kernel_launch(void* const* d_in, const int* in_sizes, int n_in,
                              void* d_out, int out_size, void* d_ws, size_t ws_size,
                              hipStream_t stream) {
  const float* feat = (const float*)d_in[0];
  const float* act  = (const float*)d_in[1];
  const float* Wq   = (const float*)d_in[2];
  const float* bq   = (const float*)d_in[3];
  const float* Wk   = (const float*)d_in[4];
  // d_in[5] = bk: cancels in softmax
  const float* Wav  = (const float*)d_in[6];
  const float* bav  = (const float*)d_in[7];
  const float* Wfv  = (const float*)d_in[8];
  const float* bfv  = (const float*)d_in[9];
  const float* W1   = (const float*)d_in[10];
  const float* b1   = (const float*)d_in[11];
  const float* W2   = (const float*)d_in[12];
  const float* b2   = (const float*)d_in[13];
  const float* W1o  = (const float*)d_in[14];
  const float* b1o  = (const float*)d_in[15];
  const float* W2o  = (const float*)d_in[16];
  const float* b2o  = (const float*)d_in[17];
  float* out = (float*)d_out;               // [0,16384): effect; rest: attn_weights
  float* ws = (float*)d_ws;

  float* ws_w  = ws;                                        // 16384
  float* ws_U  = ws + 16384;                                // 262144
  float* ws_c0 = ws + 278528;                               // 8192
  float* ws_c1 = ws + 286720;                               // 8192
  unsigned short* ws_Mbf = (unsigned short*)(ws + 294912);  // 2097152 shorts
  float* ws_W1g = ws + 1343488;                             // 163840

  hipLaunchKernelGGL(kA_prep, dim3(512), dim3(256), 0, stream,
                     feat, act, Wq, bq, Wk, Wav, bav, Wfv, bfv, W1, b1,
                     W2, b2, W1o, b1o, ws_w, ws_U, ws_c0, ws_Mbf, ws_c1,
                     ws_W1g, out + 16384);
  hipLaunchKernelGGL(kB_main, dim3(512), dim3(512), 0, stream,
                     feat, act, ws_w, ws_U, ws_W1g, ws_c0, ws_Mbf, ws_c1,
                     W2o, b2o, out);
}

// Round 18
// 140.496 us; speedup vs baseline: 1.0453x; 1.0453x over previous
//
#include <hip/hip_runtime.h>
#include <hip/hip_bf16.h>

// AttnPredictor round 18: r16 + fragment-order M storage.
// M stored as M_s[h][kc=k1>>5][col=k2][k1&31] so kB's MFMA B-fragment load
// (quad*8 within 32-k1 chunk) is perfectly coalesced (1 KB contiguous per
// wave instr vs 64 scattered 512B-strided segments), and kA's epilogue
// stores fill 64B lines instead of touching 64 lines per instr.
//  kA (512 blocks):
//   [0,64)    P1: w = softmax_d(z*(a@Wqk + bqk)/sqrt192), attn_weights
//   [64,224)  U[h,d,k] = Wfv[d,:]·W1[h,0:128,k] ; dt==4: c0'
//   [224,480) M_s (MFMA, 8 blocks/h); c1 = b2@W1o + b1o (kt==0)
//   [480,512) W1g'[h][20][256] (rows 18,19 zero)
//  kB (1024 blocks, XCD-swizzled h, 16 b per block):
//   g(regs, rank-18) -> P (bf16 LDS) -> effect = relu(P@M+c1)·W2o+b2o (MFMA)

typedef __attribute__((ext_vector_type(8))) short bf16x8;
typedef __attribute__((ext_vector_type(4))) short bf16x4;
typedef __attribute__((ext_vector_type(4))) float f32x4;

__device__ __forceinline__ short f2bf(float x) {
  unsigned u = __float_as_uint(x);
  u += 0x7fffu + ((u >> 16) & 1u);          // round-to-nearest-even
  return (short)(u >> 16);
}
__device__ __forceinline__ float bf2f(unsigned short u) {
  return __uint_as_float((unsigned)u << 16);
}

__global__ __launch_bounds__(256) void kA_prep(
    const float* __restrict__ feat, const float* __restrict__ act,
    const float* __restrict__ Wq, const float* __restrict__ bq,
    const float* __restrict__ Wk,
    const float* __restrict__ Wav, const float* __restrict__ bav,
    const float* __restrict__ Wfv, const float* __restrict__ bfv,
    const float* __restrict__ W1, const float* __restrict__ b1,
    const float* __restrict__ W2, const float* __restrict__ b2,
    const float* __restrict__ W1o, const float* __restrict__ b1o,
    float* __restrict__ ws_w, float* __restrict__ ws_U,
    float* __restrict__ ws_c0, unsigned short* __restrict__ ws_Mbf,
    float* __restrict__ ws_c1, float* __restrict__ ws_W1g,
    float* __restrict__ out_aw) {
  __shared__ __align__(16) char smem[33792];  // aliased per range
  float* sh = (float*)smem;
  const int bx = blockIdx.x;
  const int t = threadIdx.x;

  if (bx < 64) {
    // ---------------- P1: softmax weights + attn_weights (8 b per block)
    const int b0 = bx * 8;
    float* sWk = sh;                        // [192 c][32 d] transposed
    float* sA  = sh + 6144;                 // act [8][18]
    float* sQk = sh + 6320;                 // [19 j][32 d] (row 18 = bq row)
    float* sW  = sh + 6944;                 // [8][32]
#pragma unroll
    for (int i = 0; i < 24; ++i) {
      const int idx = i * 256 + t;          // idx = d*192 + c
      sWk[(idx % 192) * 32 + (idx / 192)] = Wk[idx];
    }
    if (t < 144) sA[t] = act[b0 * 18 + t];
    __syncthreads();
    for (int o = t; o < 608; o += 256) {    // Wqk[j][d]; j==18 -> bqk
      const int j = o >> 5, d = o & 31;
      const float* arow = (j < 18) ? (Wq + j * 192) : bq;
      float acc = 0.f;
      for (int c = 0; c < 192; ++c) acc += arow[c] * sWk[c * 32 + d];
      sQk[o] = acc;
    }
    __syncthreads();
    {
      const int bi = t >> 5, d = t & 31;
      float dot = sQk[18 * 32 + d];
#pragma unroll
      for (int j = 0; j < 18; ++j) dot += sA[bi * 18 + j] * sQk[j * 32 + d];
      const float z = feat[b0 * 32 + t];
      float sc = z * dot * 0.07216878364870322f;   // 1/sqrt(192)
      float mx = sc;
#pragma unroll
      for (int off = 16; off >= 1; off >>= 1) mx = fmaxf(mx, __shfl_xor(mx, off, 64));
      const float e = __expf(sc - mx);
      float s = e;
#pragma unroll
      for (int off = 16; off >= 1; off >>= 1) s += __shfl_xor(s, off, 64);
      const float w = e / s;
      ws_w[b0 * 32 + t] = w;
      sW[t] = w;
    }
    __syncthreads();
#pragma unroll
    for (int i = 0; i < 32; ++i)
      out_aw[b0 * 1024 + i * 256 + t] = sW[(i >> 2) * 32 + (t & 31)];

  } else if (bx < 224) {
    // ---------------- U range: 5 blocks per h (dt<4: 8 d's; dt==4: c0')
    const int r = bx - 64;
    const int h = r / 5, dt = r % 5;
    float* sF = sh;                         // [8][128] Wfv tile (or bfv)
    if (dt < 4) {
#pragma unroll
      for (int i = 0; i < 4; ++i) sF[i * 256 + t] = Wfv[dt * 1024 + i * 256 + t];
    } else {
      if (t < 128) sF[t] = bfv[t];
    }
    __syncthreads();
    if (dt < 4) {
      float acc[8];
#pragma unroll
      for (int dd = 0; dd < 8; ++dd) acc[dd] = 0.f;
#pragma unroll 4
      for (int fc = 0; fc < 32; ++fc) {
        float w1v[4];
#pragma unroll
        for (int u = 0; u < 4; ++u) w1v[u] = W1[(h * 192 + fc * 4 + u) * 256 + t];
#pragma unroll
        for (int dd = 0; dd < 8; ++dd) {
          float4 f4 = *(const float4*)(sF + dd * 128 + fc * 4);
          acc[dd] += f4.x * w1v[0] + f4.y * w1v[1] + f4.z * w1v[2] + f4.w * w1v[3];
        }
      }
#pragma unroll
      for (int dd = 0; dd < 8; ++dd)
        ws_U[(h * 32 + dt * 8 + dd) * 256 + t] = acc[dd];
    } else {
      float acc = b1[h * 256 + t];
      for (int fc = 0; fc < 32; ++fc) {
        float w1v[4];
#pragma unroll
        for (int u = 0; u < 4; ++u) w1v[u] = W1[(h * 192 + fc * 4 + u) * 256 + t];
        float4 f4 = *(const float4*)(sF + fc * 4);
        acc += f4.x * w1v[0] + f4.y * w1v[1] + f4.z * w1v[2] + f4.w * w1v[3];
      }
      // fold bav·W1[h,128:192,k] into c0 (bav[u] uniform -> s_load)
      for (int u = 0; u < 64; ++u)
        acc += bav[u] * W1[(h * 192 + 128 + u) * 256 + t];
      ws_c0[h * 256 + t] = acc;
    }

  } else if (bx < 480) {
    // ---------------- M range (MFMA): 8 blocks/h, 32 k1-rows each (kc = kt).
    const int r = bx - 224;
    const int h = r >> 3, kt = r & 7;
    short* sW2 = (short*)smem;              // [32][206] bf16 A-tile
    short* sB  = (short*)(smem + 13184);    // [256][38] bf16 B-chunk

    for (int i = t; i < 6144; i += 256) {
      const int row = i / 192, col = i - row * 192;
      sW2[row * 206 + col] = f2bf(W2[h * 49152 + (kt * 32 + row) * 192 + col]);
    }
    const int wv = t >> 6, lane = t & 63;
    const int quad = lane >> 4, l15 = lane & 15;

    f32x4 acc[2][4];
    const f32x4 zero = {0.f, 0.f, 0.f, 0.f};
#pragma unroll
    for (int mt = 0; mt < 2; ++mt)
#pragma unroll
      for (int nt = 0; nt < 4; ++nt) acc[mt][nt] = zero;
    float c1acc = 0.f;

    for (int kk = 0; kk < 6; ++kk) {
      __syncthreads();
#pragma unroll
      for (int vp = 0; vp < 32; vp += 2) {
        const float f0 = W1o[h * 49152 + (kk * 32 + vp) * 256 + t];
        const float f1 = W1o[h * 49152 + (kk * 32 + vp + 1) * 256 + t];
        const unsigned pack =
            ((unsigned)(unsigned short)f2bf(f1) << 16) | (unsigned short)f2bf(f0);
        *(unsigned*)(sB + t * 38 + vp) = pack;
      }
      __syncthreads();
      if (kt == 0) {
#pragma unroll
        for (int vp = 0; vp < 32; ++vp)
          c1acc += b2[h * 192 + kk * 32 + vp] * bf2f((unsigned short)sB[t * 38 + vp]);
      }
      bf16x8 a0[2];
#pragma unroll
      for (int mt = 0; mt < 2; ++mt)
        a0[mt] = *(const bf16x8*)(sW2 + (mt * 16 + l15) * 206 + kk * 32 + quad * 8);
#pragma unroll
      for (int nt = 0; nt < 4; ++nt) {
        bf16x8 b0 = *(const bf16x8*)(sB + (wv * 64 + nt * 16 + l15) * 38 + quad * 8);
#pragma unroll
        for (int mt = 0; mt < 2; ++mt)
          acc[mt][nt] = __builtin_amdgcn_mfma_f32_16x16x32_bf16(a0[mt], b0, acc[mt][nt], 0, 0, 0);
      }
    }
    // store fragment-order: M_s[h][kc=kt][col][k1&31], k1&31 = mt*16+quad*4+r
#pragma unroll
    for (int mt = 0; mt < 2; ++mt) {
#pragma unroll
      for (int nt = 0; nt < 4; ++nt) {
        const int col = wv * 64 + nt * 16 + l15;
        const unsigned p0 = ((unsigned)(unsigned short)f2bf(acc[mt][nt][1]) << 16) |
                            (unsigned short)f2bf(acc[mt][nt][0]);
        const unsigned p1 = ((unsigned)(unsigned short)f2bf(acc[mt][nt][3]) << 16) |
                            (unsigned short)f2bf(acc[mt][nt][2]);
        unsigned* dst = (unsigned*)(ws_Mbf + ((size_t)(h * 8 + kt) * 256 + col) * 32 +
                                    mt * 16 + quad * 4);
        dst[0] = p0; dst[1] = p1;
      }
    }
    if (kt == 0) ws_c1[h * 256 + t] = c1acc + b1o[h * 256 + t];

  } else {
    // ---------------- W1g' range: 1 block per h.
    const int h = bx - 480;
    float accj[18];
#pragma unroll
    for (int j = 0; j < 18; ++j) accj[j] = 0.f;
#pragma unroll 4
    for (int u = 0; u < 64; ++u) {
      const float w1v = W1[(h * 192 + 128 + u) * 256 + t];
#pragma unroll
      for (int j = 0; j < 18; ++j)
        accj[j] += Wav[j * 64 + u] * w1v;
    }
#pragma unroll
    for (int j = 0; j < 18; ++j)
      ws_W1g[(h * 20 + j) * 256 + t] = accj[j];
    ws_W1g[(h * 20 + 18) * 256 + t] = 0.f;
    ws_W1g[(h * 20 + 19) * 256 + t] = 0.f;
  }
}

// ---------------------------------------------------------------- kB: G(regs, rank-18)+P fused -> MFMA -> effect
__global__ __launch_bounds__(256) void kB_main(
    const float* __restrict__ feat, const float* __restrict__ act,
    const float* __restrict__ ws_w, const float* __restrict__ ws_U,
    const float* __restrict__ ws_W1g, const float* __restrict__ ws_c0,
    const unsigned short* __restrict__ ws_Mbf, const float* __restrict__ ws_c1,
    const float* __restrict__ W2o, const float* __restrict__ b2o,
    float* __restrict__ out_eff) {
  const int bx = blockIdx.x;
  const int h = (bx & 7) * 4 + ((bx >> 3) & 3);   // XCD swizzle (bijective in bx&31)
  const int bt = bx >> 5;                   // 16 b per block
  const int b0 = bt * 16;
  const int t = threadIdx.x;

  __shared__ __align__(16) char smem[14208];
  short* sP   = (short*)smem;               // [16][264] bf16 : 8448 B
  float* sA   = (float*)(smem + 8448);      // [16][20] act, cols 18-19 zero
  float* sZ   = (float*)(smem + 9728);      // [16][32]
  float* sWw  = (float*)(smem + 11776);     // [16][32]
  float* sRed = (float*)(smem + 13824);     // [16][4]

  // ---- stage act (zero-padded), z, w into LDS
  {
#pragma unroll
    for (int i = 0; i < 2; ++i) {
      sZ[i * 256 + t]  = feat[b0 * 32 + i * 256 + t];
      sWw[i * 256 + t] = ws_w[b0 * 32 + i * 256 + t];
    }
    for (int i = t; i < 320; i += 256) {
      const int row = i / 20, col = i - row * 20;
      sA[i] = (col < 18) ? act[(b0 + row) * 18 + col] : 0.f;
    }
  }
  __syncthreads();

  // ---- fused G(registers, rank-18) + P: thread (bq = t>>6 -> rows bq*4..+3;
  //      kg = t&63 -> cols kg*4..+3)
  {
    const int bq = t >> 6, kg = t & 63;
    float g[4][4];

    // G: g[r][c] = c0'[c] + sum_{j<20} a[row][j]*W1g'[h][j][col]
    {
      float4 c04 = *(const float4*)(ws_c0 + h * 256 + kg * 4);
#pragma unroll
      for (int r = 0; r < 4; ++r) {
        g[r][0] = c04.x; g[r][1] = c04.y; g[r][2] = c04.z; g[r][3] = c04.w;
      }
      const float* Wgp = ws_W1g + (h * 20) * 256 + kg * 4;
#pragma unroll
      for (int jc = 0; jc < 5; ++jc) {
        float w1q[4][4];
#pragma unroll
        for (int u = 0; u < 4; ++u) {
          float4 w4 = *(const float4*)(Wgp + (jc * 4 + u) * 256);
          w1q[u][0] = w4.x; w1q[u][1] = w4.y; w1q[u][2] = w4.z; w1q[u][3] = w4.w;
        }
        float a4[4][4];
#pragma unroll
        for (int r = 0; r < 4; ++r) {
          float4 av = *(const float4*)(sA + (bq * 4 + r) * 20 + jc * 4);
          a4[r][0] = av.x; a4[r][1] = av.y; a4[r][2] = av.z; a4[r][3] = av.w;
        }
#pragma unroll
        for (int u = 0; u < 4; ++u)
#pragma unroll
          for (int r = 0; r < 4; ++r)
#pragma unroll
            for (int c = 0; c < 4; ++c)
              g[r][c] += a4[r][u] * w1q[u][c];
      }
    }

    // P: acc[r][c] = sum_d w_d*relu(z_d*U[d][col] + g[r][c])
    float acc[4][4];
#pragma unroll
    for (int r = 0; r < 4; ++r) {
      acc[r][0] = 0.f; acc[r][1] = 0.f; acc[r][2] = 0.f; acc[r][3] = 0.f;
    }
    const float* Up = ws_U + h * 8192 + kg * 4;
#pragma unroll
    for (int dc = 0; dc < 8; ++dc) {
      float uc[4][4];
#pragma unroll
      for (int dd = 0; dd < 4; ++dd) {
        float4 u4 = *(const float4*)(Up + (dc * 4 + dd) * 256);
        uc[dd][0] = u4.x; uc[dd][1] = u4.y; uc[dd][2] = u4.z; uc[dd][3] = u4.w;
      }
      float zr[4][4], wr[4][4];
#pragma unroll
      for (int r = 0; r < 4; ++r) {
        float4 z4 = *(const float4*)(sZ + (bq * 4 + r) * 32 + dc * 4);
        float4 w4 = *(const float4*)(sWw + (bq * 4 + r) * 32 + dc * 4);
        zr[r][0] = z4.x; zr[r][1] = z4.y; zr[r][2] = z4.z; zr[r][3] = z4.w;
        wr[r][0] = w4.x; wr[r][1] = w4.y; wr[r][2] = w4.z; wr[r][3] = w4.w;
      }
#pragma unroll
      for (int dd = 0; dd < 4; ++dd) {
#pragma unroll
        for (int r = 0; r < 4; ++r) {
#pragma unroll
          for (int c = 0; c < 4; ++c)
            acc[r][c] += wr[r][dd] * fmaxf(zr[r][dd] * uc[dd][c] + g[r][c], 0.f);
        }
      }
    }
#pragma unroll
    for (int r = 0; r < 4; ++r) {
      bf16x4 p;
#pragma unroll
      for (int c = 0; c < 4; ++c) p[c] = f2bf(acc[r][c]);
      *(bf16x4*)(sP + (bq * 4 + r) * 264 + kg * 4) = p;
    }
  }
  __syncthreads();

  // ---- MFMA: D[16 b][64 k2 per wave] = P @ M ; epilogue
  // M_s[h][kc][col][k1&31]: wave load at (kc,nt) is 1 KB contiguous.
  {
    const int wv = t >> 6;
    const int lane = t & 63;
    const int quad = lane >> 4, l15 = lane & 15;

    f32x4 acc[4];
    const f32x4 zero = {0.f, 0.f, 0.f, 0.f};
#pragma unroll
    for (int nt = 0; nt < 4; ++nt) acc[nt] = zero;

    float c1r[4], w2r[4];
#pragma unroll
    for (int nt = 0; nt < 4; ++nt) {
      const int col = wv * 64 + nt * 16 + l15;
      c1r[nt] = ws_c1[h * 256 + col];
      w2r[nt] = W2o[h * 256 + col];
    }
    const unsigned short* Mh = ws_Mbf + (size_t)h * 8 * 256 * 32;

#pragma unroll
    for (int kc = 0; kc < 8; ++kc) {
      bf16x8 a0 = *(const bf16x8*)(sP + l15 * 264 + kc * 32 + quad * 8);
      const unsigned short* Mk = Mh + (size_t)kc * 8192 + (wv * 64) * 32;
      bf16x8 bfr[4];
#pragma unroll
      for (int nt = 0; nt < 4; ++nt)
        bfr[nt] = *(const bf16x8*)(Mk + (nt * 16 + l15) * 32 + quad * 8);
#pragma unroll
      for (int nt = 0; nt < 4; ++nt)
        acc[nt] = __builtin_amdgcn_mfma_f32_16x16x32_bf16(a0, bfr[nt], acc[nt], 0, 0, 0);
    }
#pragma unroll
    for (int r = 0; r < 4; ++r) {
      float s = fmaxf(acc[0][r] + c1r[0], 0.f) * w2r[0]
              + fmaxf(acc[1][r] + c1r[1], 0.f) * w2r[1]
              + fmaxf(acc[2][r] + c1r[2], 0.f) * w2r[2]
              + fmaxf(acc[3][r] + c1r[3], 0.f) * w2r[3];
      s += __shfl_xor(s, 1, 64);
      s += __shfl_xor(s, 2, 64);
      s += __shfl_xor(s, 4, 64);
      s += __shfl_xor(s, 8, 64);
      if (l15 == 0) sRed[(quad * 4 + r) * 4 + wv] = s;
    }
  }
  __syncthreads();
  if (t < 16) {
    float v = sRed[t * 4] + sRed[t * 4 + 1] + sRed[t * 4 + 2] + sRed[t * 4 + 3] + b2o[h];
    out_eff[(b0 + t) * 32 + h] = v;
  }
}

// ----------------------------------------------------------------
extern "C" void kernel_launch(void* const* d_in, const int* in_sizes, int n_in,
                              void* d_out, int out_size, void* d_ws, size_t ws_size,
                              hipStream_t stream) {
  const float* feat = (const float*)d_in[0];
  const float* act  = (const float*)d_in[1];
  const float* Wq   = (const float*)d_in[2];
  const float* bq   = (const float*)d_in[3];
  const float* Wk   = (const float*)d_in[4];
  // d_in[5] = bk: cancels in softmax
  const float* Wav  = (const float*)d_in[6];
  const float* bav  = (const float*)d_in[7];
  const float* Wfv  = (const float*)d_in[8];
  const float* bfv  = (const float*)d_in[9];
  const float* W1   = (const float*)d_in[10];
  const float* b1   = (const float*)d_in[11];
  const float* W2   = (const float*)d_in[12];
  const float* b2   = (const float*)d_in[13];
  const float* W1o  = (const float*)d_in[14];
  const float* b1o  = (const float*)d_in[15];
  const float* W2o  = (const float*)d_in[16];
  const float* b2o  = (const float*)d_in[17];
  float* out = (float*)d_out;               // [0,16384): effect; rest: attn_weights
  float* ws = (float*)d_ws;

  float* ws_w  = ws;                                        // 16384
  float* ws_U  = ws + 16384;                                // 262144
  float* ws_c0 = ws + 278528;                               // 8192
  float* ws_c1 = ws + 286720;                               // 8192
  unsigned short* ws_Mbf = (unsigned short*)(ws + 294912);  // 2097152 shorts
  float* ws_W1g = ws + 1343488;                             // 163840

  hipLaunchKernelGGL(kA_prep, dim3(512), dim3(256), 0, stream,
                     feat, act, Wq, bq, Wk, Wav, bav, Wfv, bfv, W1, b1,
                     W2, b2, W1o, b1o, ws_w, ws_U, ws_c0, ws_Mbf, ws_c1,
                     ws_W1g, out + 16384);
  hipLaunchKernelGGL(kB_main, dim3(1024), dim3(256), 0, stream,
                     feat, act, ws_w, ws_U, ws_W1g, ws_c0, ws_Mbf, ws_c1,
                     W2o, b2o, out);
}